// Round 1
// baseline (306.637 us; speedup 1.0000x reference)
//
#include <hip/hip_runtime.h>

typedef float  f32x4 __attribute__((ext_vector_type(4)));
typedef short  s16x8 __attribute__((ext_vector_type(8)));
typedef unsigned short u16;

// ---- workspace layout (bytes) ----
#define OFF_E     0ULL           // e  bf16 [65536][128]          16 MiB
#define OFF_ET    16777216ULL    // eT bf16 [8][128][8192]        16 MiB
#define OFF_EPART 33554432ULL    // Epart f32 [8][8][128][512]    16 MiB
#define OFF_GT    50331648ULL    // Gt bf16 [8][512][128]          1 MiB
#define OFF_WT    51380224ULL    // Wt bf16 [128][512]           128 KiB
#define OFF_ZP    51511296ULL    // zpart f32 [512][128]         256 KiB
#define OFF_RZ2   51773440ULL    // rz2 f32 [1024]                 4 KiB
#define WS_NEED   51777536ULL

__device__ __forceinline__ u16 f2bf(float f) {
  unsigned u = __float_as_uint(f);
  return (u16)((u + 0x8000u) >> 16);          // round-half-up to bf16
}
__device__ __forceinline__ unsigned pack2(float a, float b) {
  unsigned ua = __float_as_uint(a), ub = __float_as_uint(b);
  return ((ua + 0x8000u) >> 16) | ((ub + 0x8000u) & 0xffff0000u);
}

// ------------------------------------------------------------------
// k_wt: Wt[h][c] = bf16(W[c][h])
__global__ __launch_bounds__(256) void k_wt(const float* __restrict__ W,
                                            u16* __restrict__ Wt) {
  int idx = blockIdx.x * 256 + threadIdx.x;    // 65536 total
  int h = idx & 127, c = idx >> 7;
  Wt[h * 512 + c] = f2bf(W[c * 128 + h]);
}

// ------------------------------------------------------------------
// k_logits_e: per 128-row tile: logits = x@Wt (bf16 MFMA), then
// e = exp(logits) -> writes e (natural) + eT (transposed) bf16, and
// per-column partial sums of e (zpart).
__global__ __launch_bounds__(256) void k_logits_e(
    const float* __restrict__ x, const u16* __restrict__ Wt,
    u16* __restrict__ e, u16* __restrict__ eT, float* __restrict__ zpart) {
  __shared__ __align__(16) u16 sm[128 * 128];  // k-loop: lA(8K)+lB(8K); epilogue: e-tile 16K
  __shared__ float zs[512];
  u16* lA = sm;
  u16* lB = sm + 8192;
  const int tid = threadIdx.x;
  const int lane = tid & 63, wave = tid >> 6;
  const int l15 = lane & 15, quad = lane >> 4;
  const int mt = blockIdx.x;                   // 0..511
  const int rowBase = mt << 7;

  f32x4 acc[2][8];
#pragma unroll
  for (int i = 0; i < 2; ++i)
#pragma unroll
    for (int j = 0; j < 8; ++j) acc[i][j] = (f32x4){0.f, 0.f, 0.f, 0.f};

  for (int kt = 0; kt < 8; ++kt) {
    const int k0 = kt << 6;
    if (kt) __syncthreads();
    // stage A: x rows (m=s, k=c), cvt->bf16, swizzled 16B chunks (key r&7)
    {
      const int q = tid & 3, rb = tid >> 2;
#pragma unroll
      for (int rep = 0; rep < 2; ++rep) {
        const int r = rb + rep * 64;
        const float* src = x + (size_t)(rowBase + r) * 512 + k0 + q * 4;
#pragma unroll
        for (int j = 0; j < 4; ++j) {
          f32x4 v = *(const f32x4*)(src + j * 16);
          const int chunk = (2 * j + (q >> 1)) ^ (r & 7);
          unsigned* dst = (unsigned*)&lA[r * 64 + chunk * 8 + (q & 1) * 4];
          dst[0] = pack2(v[0], v[1]);
          dst[1] = pack2(v[2], v[3]);
        }
      }
    }
    // stage B: Wt rows (n=h, k=c), straight bf16 copy
    {
      const int oct = tid & 7, rb = tid >> 3;
#pragma unroll
      for (int rep = 0; rep < 4; ++rep) {
        const int r = rb + rep * 32;
        s16x8 v = *(const s16x8*)(Wt + r * 512 + k0 + oct * 8);
        *(s16x8*)&lB[r * 64 + ((oct ^ (r & 7)) * 8)] = v;
      }
    }
    __syncthreads();
#pragma unroll
    for (int kk = 0; kk < 2; ++kk) {
      s16x8 af[2], bf[8];
#pragma unroll
      for (int i = 0; i < 2; ++i) {
        const int r = wave * 32 + i * 16 + l15;
        af[i] = *(const s16x8*)&lA[r * 64 + (((kk * 4 + quad) ^ (r & 7)) * 8)];
      }
#pragma unroll
      for (int j = 0; j < 8; ++j) {
        const int r = j * 16 + l15;
        bf[j] = *(const s16x8*)&lB[r * 64 + (((kk * 4 + quad) ^ (r & 7)) * 8)];
      }
#pragma unroll
      for (int i = 0; i < 2; ++i)
#pragma unroll
        for (int j = 0; j < 8; ++j)
          acc[i][j] = __builtin_amdgcn_mfma_f32_16x16x32_bf16(af[i], bf[j], acc[i][j], 0, 0, 0);
    }
  }

  // ---- epilogue: exp, column sums, e/eT writes ----
  float ex[2][8][4];
  float cs[8];
#pragma unroll
  for (int j = 0; j < 8; ++j) cs[j] = 0.f;
#pragma unroll
  for (int i = 0; i < 2; ++i)
#pragma unroll
    for (int j = 0; j < 8; ++j)
#pragma unroll
      for (int rr = 0; rr < 4; ++rr) {
        float l = acc[i][j][rr];
        l = fminf(fmaxf(l, -30.f), 30.f);
        float t = __expf(l);
        ex[i][j][rr] = t;
        cs[j] += t;
      }
#pragma unroll
  for (int j = 0; j < 8; ++j) {
    cs[j] += __shfl_xor(cs[j], 16);
    cs[j] += __shfl_xor(cs[j], 32);
  }
  if (quad == 0) {
#pragma unroll
    for (int j = 0; j < 8; ++j) zs[wave * 128 + j * 16 + l15] = cs[j];
  }
  __syncthreads();  // frag reads done; zs visible

  // e-tile to LDS [s][h], 16B-chunk swizzle key (s&15)
#pragma unroll
  for (int i = 0; i < 2; ++i)
#pragma unroll
    for (int j = 0; j < 8; ++j)
#pragma unroll
      for (int rr = 0; rr < 4; ++rr) {
        int s = wave * 32 + i * 16 + quad * 4 + rr;
        int h = j * 16 + l15;
        sm[s * 128 + (((h >> 3) ^ (s & 15)) * 8) + (h & 7)] = f2bf(ex[i][j][rr]);
      }
  if (tid < 128)
    zpart[mt * 128 + tid] = zs[tid] + zs[128 + tid] + zs[256 + tid] + zs[384 + tid];
  __syncthreads();

  // e natural write (b128 rows)
  {
    int s = tid >> 1;
#pragma unroll
    for (int i = 0; i < 8; ++i) {
      int c = (tid & 1) * 8 + i;
      s16x8 v = *(const s16x8*)&sm[s * 128 + ((c ^ (s & 15)) * 8)];
      *(s16x8*)(e + (size_t)(rowBase + s) * 128 + c * 8) = v;
    }
  }
  // eT write: gather 8 s per h, b128 stores
  {
    int ck = tid & 15, hb = tid >> 4;
    int b = mt >> 6;
    int sBase = (mt & 63) << 7;
#pragma unroll
    for (int pass = 0; pass < 8; ++pass) {
      int h = hb + pass * 16;
      s16x8 v;
#pragma unroll
      for (int j = 0; j < 8; ++j) {
        int s = ck * 8 + j;
        v[j] = (short)sm[s * 128 + (((h >> 3) ^ (s & 15)) * 8) + (h & 7)];
      }
      *(s16x8*)(eT + (size_t)(b * 128 + h) * 8192 + sBase + ck * 8) = v;
    }
  }
}

// ------------------------------------------------------------------
// k_zmerge: Z per (b,h), store 1/Z^2
__global__ __launch_bounds__(256) void k_zmerge(const float* __restrict__ zpart,
                                                float* __restrict__ rz2) {
  int gid = blockIdx.x * 256 + threadIdx.x;  // 0..1023
  int b = gid >> 7, h = gid & 127;
  float z = 0.f;
  for (int i = 0; i < 64; ++i) z += zpart[(b * 64 + i) * 128 + h];
  rz2[gid] = 1.0f / (z * z);
}

// ------------------------------------------------------------------
// k_E: Epart[kc][b][h][c-band] = eT(chunk) @ x(chunk); split-K over s.
__global__ __launch_bounds__(256) void k_E(const float* __restrict__ x,
                                           const u16* __restrict__ eT,
                                           float* __restrict__ Epart) {
  __shared__ __align__(16) u16 lA[128 * 64];
  __shared__ __align__(16) u16 lB[64 * 64];
  const int tid = threadIdx.x;
  const int lane = tid & 63, wave = tid >> 6;
  const int l15 = lane & 15, quad = lane >> 4;
  const int nt = blockIdx.x;  // c-band 0..7 (64 cols)
  const int b = blockIdx.y;
  const int kc = blockIdx.z;  // s-chunk 0..7 (1024 rows)

  f32x4 acc[2][4];
#pragma unroll
  for (int i = 0; i < 2; ++i)
#pragma unroll
    for (int j = 0; j < 4; ++j) acc[i][j] = (f32x4){0.f, 0.f, 0.f, 0.f};

  for (int kt = 0; kt < 16; ++kt) {
    const int sb = kc * 1024 + kt * 64;
    if (kt) __syncthreads();
    // A: eT rows (m=h, k=s), straight copy
    {
      const int oct = tid & 7, rb = tid >> 3;
#pragma unroll
      for (int rep = 0; rep < 4; ++rep) {
        const int r = rb + rep * 32;
        s16x8 v = *(const s16x8*)(eT + (size_t)(b * 128 + r) * 8192 + sb + oct * 8);
        *(s16x8*)&lA[r * 64 + ((oct ^ (r & 7)) * 8)] = v;
      }
    }
    // B: x chunk transposed to [c][s], packed-pair b32 writes, swizzle key (c>>3)&7
    {
      const int cq = tid & 15, sp = tid >> 4;
#pragma unroll
      for (int p = 0; p < 2; ++p) {
        const int sl = p * 32 + sp * 2;
        const float* src = x + (size_t)(b * 8192 + sb + sl) * 512 + nt * 64 + cq * 4;
        f32x4 v0 = *(const f32x4*)src;
        f32x4 v1 = *(const f32x4*)(src + 512);
#pragma unroll
        for (int i = 0; i < 4; ++i) {
          const int c = cq * 4 + i;
          const int chunk = ((sl >> 3) & 7) ^ ((c >> 3) & 7);
          *(unsigned*)&lB[c * 64 + chunk * 8 + (sl & 7)] = pack2(v0[i], v1[i]);
        }
      }
    }
    __syncthreads();
#pragma unroll
    for (int kk = 0; kk < 2; ++kk) {
      s16x8 af[2], bf[4];
#pragma unroll
      for (int i = 0; i < 2; ++i) {
        const int r = wave * 32 + i * 16 + l15;
        af[i] = *(const s16x8*)&lA[r * 64 + (((kk * 4 + quad) ^ (r & 7)) * 8)];
      }
#pragma unroll
      for (int j = 0; j < 4; ++j) {
        const int n = j * 16 + l15;
        bf[j] = *(const s16x8*)&lB[n * 64 + (((kk * 4 + quad) ^ ((n >> 3) & 7)) * 8)];
      }
#pragma unroll
      for (int i = 0; i < 2; ++i)
#pragma unroll
        for (int j = 0; j < 4; ++j)
          acc[i][j] = __builtin_amdgcn_mfma_f32_16x16x32_bf16(af[i], bf[j], acc[i][j], 0, 0, 0);
    }
  }
  float* dst = Epart + (size_t)(kc * 8 + b) * 128 * 512 + nt * 64;
#pragma unroll
  for (int i = 0; i < 2; ++i)
#pragma unroll
    for (int j = 0; j < 4; ++j)
#pragma unroll
      for (int rr = 0; rr < 4; ++rr) {
        int h = wave * 32 + i * 16 + quad * 4 + rr;
        int c = j * 16 + l15;
        dst[(size_t)h * 512 + c] = acc[i][j][rr];
      }
}

// ------------------------------------------------------------------
// k_G: Gt[b][c][h] = bf16( (sum_kc Epart) * rz2[b,h] )
__global__ __launch_bounds__(256) void k_G(const float* __restrict__ Epart,
                                           const float* __restrict__ rz2,
                                           u16* __restrict__ Gt) {
  int idx = blockIdx.x * 256 + threadIdx.x;  // < 524288
  int c = idx & 511, h = (idx >> 9) & 127, b = idx >> 16;
  float s = 0.f;
#pragma unroll
  for (int p = 0; p < 8; ++p) s += Epart[((size_t)(p * 8 + b) * 128 + h) * 512 + c];
  Gt[(size_t)(b * 512 + c) * 128 + h] = f2bf(s * rz2[b * 128 + h]);
}

// ------------------------------------------------------------------
// k_out: out[s][c] = e[s][:] @ G[:, c]  (A = e natural, B = Gt natural)
__global__ __launch_bounds__(256) void k_out(const u16* __restrict__ e,
                                             const u16* __restrict__ Gt,
                                             float* __restrict__ out) {
  __shared__ __align__(16) u16 lA[128 * 128];
  __shared__ __align__(16) u16 lB[128 * 128];
  const int tid = threadIdx.x;
  const int lane = tid & 63, wave = tid >> 6;
  const int l15 = lane & 15, quad = lane >> 4;
  const int st = blockIdx.x;  // s-tile 0..63
  const int b = blockIdx.y;

  // stage A once (K = 128 fully resident)
  {
    const int hx = tid & 15, rb = tid >> 4;
#pragma unroll
    for (int pass = 0; pass < 8; ++pass) {
      const int r = rb + pass * 16;
      s16x8 v = *(const s16x8*)(e + (size_t)(b * 8192 + st * 128 + r) * 128 + hx * 8);
      *(s16x8*)&lA[r * 128 + ((hx ^ (r & 15)) * 8)] = v;
    }
  }
  for (int ct = 0; ct < 4; ++ct) {
    __syncthreads();
    {
      const int hx = tid & 15, rb = tid >> 4;
#pragma unroll
      for (int pass = 0; pass < 8; ++pass) {
        const int r = rb + pass * 16;
        s16x8 v = *(const s16x8*)(Gt + (size_t)(b * 512 + ct * 128 + r) * 128 + hx * 8);
        *(s16x8*)&lB[r * 128 + ((hx ^ (r & 15)) * 8)] = v;
      }
    }
    __syncthreads();
    f32x4 acc[2][8];
#pragma unroll
    for (int i = 0; i < 2; ++i)
#pragma unroll
      for (int j = 0; j < 8; ++j) acc[i][j] = (f32x4){0.f, 0.f, 0.f, 0.f};
#pragma unroll
    for (int kk = 0; kk < 4; ++kk) {
      s16x8 af[2], bf[8];
#pragma unroll
      for (int i = 0; i < 2; ++i) {
        const int r = wave * 32 + i * 16 + l15;
        af[i] = *(const s16x8*)&lA[r * 128 + (((kk * 4 + quad) ^ (r & 15)) * 8)];
      }
#pragma unroll
      for (int j = 0; j < 8; ++j) {
        const int n = j * 16 + l15;
        bf[j] = *(const s16x8*)&lB[n * 128 + (((kk * 4 + quad) ^ (n & 15)) * 8)];
      }
#pragma unroll
      for (int i = 0; i < 2; ++i)
#pragma unroll
        for (int j = 0; j < 8; ++j)
          acc[i][j] = __builtin_amdgcn_mfma_f32_16x16x32_bf16(af[i], bf[j], acc[i][j], 0, 0, 0);
    }
#pragma unroll
    for (int i = 0; i < 2; ++i)
#pragma unroll
      for (int j = 0; j < 8; ++j)
#pragma unroll
        for (int rr = 0; rr < 4; ++rr) {
          int s = wave * 32 + i * 16 + quad * 4 + rr;
          int c = j * 16 + l15;
          out[(size_t)(b * 8192 + st * 128 + s) * 512 + ct * 128 + c] = acc[i][j][rr];
        }
  }
}

// ------------------------------------------------------------------
extern "C" void kernel_launch(void* const* d_in, const int* in_sizes, int n_in,
                              void* d_out, int out_size, void* d_ws, size_t ws_size,
                              hipStream_t stream) {
  if (ws_size < (size_t)WS_NEED) return;  // need ~49.4 MiB scratch
  const float* x = (const float*)d_in[0];
  const float* W = (const float*)d_in[1];
  // d_in[2] = bias: softmax over S is invariant to per-h constants -> ignored
  float* out = (float*)d_out;
  char* ws = (char*)d_ws;
  u16* e = (u16*)(ws + OFF_E);
  u16* eT = (u16*)(ws + OFF_ET);
  float* Epart = (float*)(ws + OFF_EPART);
  u16* Gt = (u16*)(ws + OFF_GT);
  u16* Wt = (u16*)(ws + OFF_WT);
  float* zpart = (float*)(ws + OFF_ZP);
  float* rz2 = (float*)(ws + OFF_RZ2);

  k_wt<<<256, 256, 0, stream>>>(W, Wt);
  k_logits_e<<<512, 256, 0, stream>>>(x, Wt, e, eT, zpart);
  k_zmerge<<<4, 256, 0, stream>>>(zpart, rz2);
  k_E<<<dim3(8, 8, 8), 256, 0, stream>>>(x, eT, Epart);
  k_G<<<2048, 256, 0, stream>>>(Epart, rz2, Gt);
  k_out<<<dim3(64, 8), 256, 0, stream>>>(e, Gt, out);
}